// Round 1
// baseline (1487.367 us; speedup 1.0000x reference)
//
#include <hip/hip_runtime.h>

// ---------------------------------------------------------------------------
// RGAT: 3 edge types (writes: author->paper, cites: paper->paper,
// publishes: venue->paper), single-head GAT conv each, summed into paper out.
//
// Key algebra: s_src = x_src @ (W_src @ a_src), s_dst = x_dst @ (W_dst @ a_dst)
// -> no h_dst GEMMs needed; all score vectors are extra columns of an
// extended weight matrix (N = 80 = 64 h-cols + up to 4 score cols).
// Softmax without segment-max: |e| <= ~10 so exp(e) is fp32-safe.
// ---------------------------------------------------------------------------

#define F_IN 768
#define C_OUT 64
#define BN 80     // 64 h cols + 16 extra (score cols in 64..67)
#define TILE_M 64
#define BK 64
#define LDK 72    // padded LDS k-stride (bf16 elems): 144 B rows, 16B-aligned

typedef __bf16 bf16x8 __attribute__((ext_vector_type(8)));
typedef float  f32x4  __attribute__((ext_vector_type(4)));

// ---------------------------------------------------------------------------
// Build WextT[80][768] bf16 per node-type GEMM:
//   cols 0..63  = W_src (transposed)
//   col  64     = u = W_src @ a_src          (-> s_src)
//   cols 65..67 = v_* = W*_dst @ a*_dst      (paper GEMM only -> s_dst's)
//   rest zero
// ---------------------------------------------------------------------------
__global__ void prep_weights(
    const float* __restrict__ Ww_src, const float* __restrict__ aw_src,
    const float* __restrict__ Wc_src, const float* __restrict__ ac_src,
    const float* __restrict__ Wp_src, const float* __restrict__ ap_src,
    const float* __restrict__ Ww_dst, const float* __restrict__ aw_dst,
    const float* __restrict__ Wc_dst, const float* __restrict__ ac_dst,
    const float* __restrict__ Wp_dst, const float* __restrict__ ap_dst,
    __bf16* __restrict__ WTw, __bf16* __restrict__ WTc, __bf16* __restrict__ WTp)
{
    int type = blockIdx.x;  // 0=author GEMM(writes), 1=paper GEMM(cites), 2=venue GEMM(pub)
    const float* Ws = (type == 0) ? Ww_src : (type == 1) ? Wc_src : Wp_src;
    const float* as = (type == 0) ? aw_src : (type == 1) ? ac_src : ap_src;
    __bf16* WT = (type == 0) ? WTw : (type == 1) ? WTc : WTp;

    for (int r = threadIdx.x; r < F_IN; r += blockDim.x) {
        const float* wrow = Ws + (size_t)r * C_OUT;
        float u = 0.f;
        for (int c = 0; c < C_OUT; ++c) {
            float wv = wrow[c];
            WT[(size_t)c * F_IN + r] = (__bf16)wv;
            u += wv * as[c];
        }
        WT[(size_t)64 * F_IN + r] = (__bf16)u;
        for (int c = 65; c < BN; ++c) WT[(size_t)c * F_IN + r] = (__bf16)0.f;
        if (type == 1) {
            const float* r1 = Ww_dst + (size_t)r * C_OUT;
            const float* r2 = Wc_dst + (size_t)r * C_OUT;
            const float* r3 = Wp_dst + (size_t)r * C_OUT;
            float vw = 0.f, vc = 0.f, vp = 0.f;
            for (int c = 0; c < C_OUT; ++c) {
                vw += r1[c] * aw_dst[c];
                vc += r2[c] * ac_dst[c];
                vp += r3[c] * ap_dst[c];
            }
            WT[(size_t)65 * F_IN + r] = (__bf16)vw;
            WT[(size_t)66 * F_IN + r] = (__bf16)vc;
            WT[(size_t)67 * F_IN + r] = (__bf16)vp;
        }
    }
}

// ---------------------------------------------------------------------------
// Fused GEMM: H[M,64] = X[M,768] @ Wext (bf16 MFMA, fp32 acc)
// plus score columns 64..67 scattered to s0..s3 (null = unused).
// Block: 256 thr (4 waves), 64 rows x 80 cols, K-chunks of 64.
// ---------------------------------------------------------------------------
__global__ __launch_bounds__(256) void gemm_fused(
    const float* __restrict__ X, const __bf16* __restrict__ WT,
    float* __restrict__ H,
    float* __restrict__ s0, float* __restrict__ s1,
    float* __restrict__ s2, float* __restrict__ s3, int M)
{
    __shared__ __bf16 As[TILE_M][LDK];
    __shared__ __bf16 Bs[BN][LDK];

    const int tid  = threadIdx.x;
    const int lane = tid & 63;
    const int warp = tid >> 6;
    const int colq = lane & 15;
    const int quad = lane >> 4;
    const int rowBase = blockIdx.x * TILE_M;

    f32x4 acc[5];
#pragma unroll
    for (int t = 0; t < 5; ++t) acc[t] = (f32x4){0.f, 0.f, 0.f, 0.f};

    const int arow  = tid >> 2;          // 0..63
    const int akoff = (tid & 3) * 16;    // 0,16,32,48
    const int grow  = rowBase + arow;
    const bool rowOK = grow < M;
    const float* xrow = X + (size_t)grow * F_IN;

    for (int kc = 0; kc < F_IN; kc += BK) {
        // ---- stage A tile (fp32 -> bf16) ----
        f32x4 av[4];
        if (rowOK) {
            const f32x4* xp = (const f32x4*)(xrow + kc + akoff);
            av[0] = xp[0]; av[1] = xp[1]; av[2] = xp[2]; av[3] = xp[3];
        } else {
#pragma unroll
            for (int i = 0; i < 4; ++i) av[i] = (f32x4){0.f, 0.f, 0.f, 0.f};
        }
        bf16x8 cv[2];
#pragma unroll
        for (int i = 0; i < 4; ++i)
#pragma unroll
            for (int j = 0; j < 4; ++j)
                cv[i >> 1][(i & 1) * 4 + j] = (__bf16)av[i][j];
        *(bf16x8*)&As[arow][akoff]     = cv[0];
        *(bf16x8*)&As[arow][akoff + 8] = cv[1];

        // ---- stage B tile (already bf16, WextT is [80][768]) ----
        for (int c = tid; c < (BN * BK / 8); c += 256) {   // 640 chunks of 8 bf16
            int br = c >> 3, bo = (c & 7) * 8;
            *(bf16x8*)&Bs[br][bo] =
                *(const bf16x8*)&WT[(size_t)br * F_IN + kc + bo];
        }
        __syncthreads();

        // ---- MFMA ----
#pragma unroll
        for (int kk = 0; kk < BK; kk += 32) {
            bf16x8 a = *(const bf16x8*)&As[warp * 16 + colq][kk + quad * 8];
#pragma unroll
            for (int t = 0; t < 5; ++t) {
                bf16x8 b = *(const bf16x8*)&Bs[t * 16 + colq][kk + quad * 8];
                acc[t] = __builtin_amdgcn_mfma_f32_16x16x32_bf16(a, b, acc[t], 0, 0, 0);
            }
        }
        __syncthreads();
    }

    // ---- epilogue: C/D layout col=lane&15, row=quad*4+reg ----
    const int orow0 = rowBase + warp * 16 + quad * 4;
#pragma unroll
    for (int r = 0; r < 4; ++r) {
        int row = orow0 + r;
        if (row < M) {
#pragma unroll
            for (int t = 0; t < 4; ++t)
                H[(size_t)row * C_OUT + t * 16 + colq] = acc[t][r];
            if (colq < 4) {
                float* sp = (colq == 0) ? s0 : (colq == 1) ? s1 : (colq == 2) ? s2 : s3;
                if (sp) sp[row] = acc[4][r];
            }
        }
    }
}

// ---------------------------------------------------------------------------
// out[i] = bw[c] + bc[c] + bp[c]  (combined bias init; out re-poisoned per call)
// ---------------------------------------------------------------------------
__global__ void init_out(const float* __restrict__ bw, const float* __restrict__ bc,
                         const float* __restrict__ bp, float* __restrict__ out, int n)
{
    int i = blockIdx.x * blockDim.x + threadIdx.x;
    if (i < n) {
        int c = i & 63;
        out[i] = bw[c] + bc[c] + bp[c];
    }
}

// ---------------------------------------------------------------------------
// Pass 1 per edge type: w = exp(leaky_relu(s_src[src]+s_dst[dst])),
// denom[dst] += w. (no segment-max: |e| <= ~10, fp32-safe)
// ---------------------------------------------------------------------------
__global__ void edge_score(const float* __restrict__ sS, const float* __restrict__ sD,
                           const int* __restrict__ src, const int* __restrict__ dst,
                           float* __restrict__ wbuf, float* __restrict__ denom, int E)
{
    int i = blockIdx.x * blockDim.x + threadIdx.x;
    int stride = gridDim.x * blockDim.x;
    for (; i < E; i += stride) {
        float e = sS[src[i]] + sD[dst[i]];
        e = (e >= 0.f) ? e : 0.2f * e;
        float w = __expf(e);
        wbuf[i] = w;
        atomicAdd(&denom[dst[i]], w);
    }
}

// ---------------------------------------------------------------------------
// Pass 2 per edge type: out[dst] += (w/denom[dst]) * H[src]   (wave per edge)
// ---------------------------------------------------------------------------
__global__ void edge_scatter(const float* __restrict__ H, const float* __restrict__ wbuf,
                             const float* __restrict__ denom, const int* __restrict__ src,
                             const int* __restrict__ dst, float* __restrict__ out, int E)
{
    const int lane = threadIdx.x & 63;
    int wid = (blockIdx.x * blockDim.x + threadIdx.x) >> 6;
    const int nw = (gridDim.x * blockDim.x) >> 6;
    for (int e = wid; e < E; e += nw) {
        int s = src[e], d = dst[e];
        float alpha = wbuf[e] / (denom[d] + 1e-16f);
        float v = H[(size_t)s * C_OUT + lane] * alpha;
        atomicAdd(&out[(size_t)d * C_OUT + lane], v);
    }
}

// ---------------------------------------------------------------------------
extern "C" void kernel_launch(void* const* d_in, const int* in_sizes, int n_in,
                              void* d_out, int out_size, void* d_ws, size_t ws_size,
                              hipStream_t stream)
{
    const float* x_a = (const float*)d_in[0];
    const float* x_p = (const float*)d_in[1];
    const float* x_v = (const float*)d_in[2];
    const int* w_src = (const int*)d_in[3];
    const int* w_dst = (const int*)d_in[4];
    const int* c_src = (const int*)d_in[5];
    const int* c_dst = (const int*)d_in[6];
    const int* p_src = (const int*)d_in[7];
    const int* p_dst = (const int*)d_in[8];
    const float* Ww_src = (const float*)d_in[9];
    const float* Ww_dst = (const float*)d_in[10];
    const float* aw_src = (const float*)d_in[11];
    const float* aw_dst = (const float*)d_in[12];
    const float* bw     = (const float*)d_in[13];
    const float* Wc_src = (const float*)d_in[14];
    const float* Wc_dst = (const float*)d_in[15];
    const float* ac_src = (const float*)d_in[16];
    const float* ac_dst = (const float*)d_in[17];
    const float* bc     = (const float*)d_in[18];
    const float* Wp_src = (const float*)d_in[19];
    const float* Wp_dst = (const float*)d_in[20];
    const float* ap_src = (const float*)d_in[21];
    const float* ap_dst = (const float*)d_in[22];
    const float* bp     = (const float*)d_in[23];
    float* out = (float*)d_out;

    const int Na = in_sizes[0] / F_IN;
    const int Np = in_sizes[1] / F_IN;
    const int Nv = in_sizes[2] / F_IN;
    const int Ew = in_sizes[3];
    const int Ec = in_sizes[5];
    const int Ep = in_sizes[7];

    // ---- workspace layout ----
    char* ws = (char*)d_ws;
    size_t off = 0;
    auto alloc = [&](size_t bytes) -> void* {
        off = (off + 255) & ~(size_t)255;
        void* p = ws + off;
        off += bytes;
        return p;
    };
    __bf16* WTw = (__bf16*)alloc((size_t)BN * F_IN * 2);
    __bf16* WTc = (__bf16*)alloc((size_t)BN * F_IN * 2);
    __bf16* WTp = (__bf16*)alloc((size_t)BN * F_IN * 2);
    float* Ha = (float*)alloc((size_t)Na * C_OUT * 4);
    float* Hp = (float*)alloc((size_t)Np * C_OUT * 4);
    float* Hv = (float*)alloc((size_t)Nv * C_OUT * 4);
    float* s_w_src = (float*)alloc((size_t)Na * 4);
    float* s_c_src = (float*)alloc((size_t)Np * 4);
    float* s_p_src = (float*)alloc((size_t)Nv * 4);
    float* s_w_dst = (float*)alloc((size_t)Np * 4);
    float* s_c_dst = (float*)alloc((size_t)Np * 4);
    float* s_p_dst = (float*)alloc((size_t)Np * 4);
    float* den = (float*)alloc((size_t)3 * Np * 4);   // contiguous: one memset
    float* den_w = den, *den_c = den + Np, *den_p = den + 2 * Np;
    float* wb_w = (float*)alloc((size_t)Ew * 4);
    float* wb_c = (float*)alloc((size_t)Ec * 4);
    float* wb_p = (float*)alloc((size_t)Ep * 4);
    (void)ws_size; (void)n_in; (void)out_size;

    hipMemsetAsync(den, 0, (size_t)3 * Np * 4, stream);

    prep_weights<<<3, 256, 0, stream>>>(
        Ww_src, aw_src, Wc_src, ac_src, Wp_src, ap_src,
        Ww_dst, aw_dst, Wc_dst, ac_dst, Wp_dst, ap_dst,
        WTw, WTc, WTp);

    gemm_fused<<<(Na + TILE_M - 1) / TILE_M, 256, 0, stream>>>(
        x_a, WTw, Ha, s_w_src, nullptr, nullptr, nullptr, Na);
    gemm_fused<<<(Np + TILE_M - 1) / TILE_M, 256, 0, stream>>>(
        x_p, WTc, Hp, s_c_src, s_w_dst, s_c_dst, s_p_dst, Np);
    gemm_fused<<<(Nv + TILE_M - 1) / TILE_M, 256, 0, stream>>>(
        x_v, WTp, Hv, s_p_src, nullptr, nullptr, nullptr, Nv);

    init_out<<<(Np * C_OUT + 255) / 256, 256, 0, stream>>>(bw, bc, bp, out, Np * C_OUT);

    edge_score<<<1024, 256, 0, stream>>>(s_w_src, s_w_dst, w_src, w_dst, wb_w, den_w, Ew);
    edge_score<<<2048, 256, 0, stream>>>(s_c_src, s_c_dst, c_src, c_dst, wb_c, den_c, Ec);
    edge_score<<<1024, 256, 0, stream>>>(s_p_src, s_p_dst, p_src, p_dst, wb_p, den_p, Ep);

    edge_scatter<<<2048, 256, 0, stream>>>(Ha, wb_w, den_w, w_src, w_dst, out, Ew);
    edge_scatter<<<4096, 256, 0, stream>>>(Hp, wb_c, den_c, c_src, c_dst, out, Ec);
    edge_scatter<<<2048, 256, 0, stream>>>(Hv, wb_p, den_p, p_src, p_dst, out, Ep);
}